// Round 5
// baseline (208.618 us; speedup 1.0000x reference)
//
#include <hip/hip_runtime.h>

// NeuralHMM forward, B=32, T=4096, K=16, fp32.
// Outputs flat: beliefs[B,T,K], log_beliefs[B,T,K], log_normalizers[B,T], A[B,T,K,K]
//
// Chunked parallel scan, 4 kernels, no d_ws, no conditional launches:
//  K1 (fused): blocks 0..503 compose per-chunk 16x16 transfer operators G
//      (leak-free, rescale every 4 steps) into the beliefs region; blocks 504+
//      write A (one float4/thread) SKIPPING the first 128KB corner (Pst stash).
//  K2: serial scan over 64 chunk operators per batch -> P_start into A corner.
//  K3: replay, 4 distinct chunks per wave (row-local DPP), depth-4 pipeline;
//      overwrites beliefs region with real outputs.
//  K4: a_fix rewrites the 128KB A corner (runs after K3 read the stash).

#define BB 32
#define TT 4096
#define KK 16
#define LCH 64
#define NCH 64
#define NP1 504        // phase1 blocks in fused kernel
#define CORNER4 8192   // float4s in the Pst corner (32768 floats = 128KB)
#define NA  32736      // A-writer blocks in k1 (8380416 float4s)

constexpr float RHO  = 0.001f;
constexpr float LEAK = 1e-10f;

template<int CTRL>
__device__ __forceinline__ float dppf(float x) {
  return __uint_as_float((unsigned)__builtin_amdgcn_update_dpp(
      0, (int)__float_as_uint(x), CTRL, 0xF, 0xF, true));
}
// sum across each 16-lane row (row-local; all lanes get the row total)
__device__ __forceinline__ float sum16(float x) {
  x += dppf<0xB1>(x);   // xor 1
  x += dppf<0x4E>(x);   // xor 2
  x += dppf<0x141>(x);  // xor 7
  x += dppf<0x140>(x);  // xor 15
  return x;
}
__device__ __forceinline__ float rdfirst(float x) {
  return __uint_as_float((unsigned)__builtin_amdgcn_readfirstlane((int)__float_as_uint(x)));
}

__device__ __forceinline__ void write_A4(const float* __restrict__ bp,
                                         float* __restrict__ Aout, long tid) {
  long flat = tid * 4;
  int  bt   = (int)(flat >> 8);
  int  rem  = (int)(flat & 255);
  int  r    = rem >> 4;
  int  c0   = rem & 15;
  float p   = bp[bt];
  float eta = fminf(fmaxf(0.02f + 0.33f * p, 0.001f), 0.95f);
  float diag, s;
  if (r == 0)       { diag = 1.0f - eta; s = (1.0f - eta) + eta; }
  else if (r == 15) { diag = 1.0f - RHO; s = RHO + (1.0f - RHO); }
  else { diag = fmaxf((1.0f - eta) - RHO, 0.01f); s = (RHO + diag) + eta; }
  s = fmaxf(s, 1e-8f);
  float inv = 1.0f / s;
  float4 v;
  float* vp = &v.x;
  #pragma unroll
  for (int q = 0; q < 4; ++q) {
    int cc = c0 + q;
    float a = (cc == r) ? diag : (cc == r + 1) ? eta : (cc == r - 1) ? RHO : 0.0f;
    vp[q] = a * inv;
  }
  ((float4*)Aout)[tid] = v;
}

// ---------------- K1 fused: chunk composition + A writer (skips corner) ----
__global__ __launch_bounds__(256) void k1_fused(
    const float* __restrict__ em, const float* __restrict__ bp,
    const float* __restrict__ msk, float* __restrict__ Gbuf,
    float* __restrict__ Aout)
{
  const int bid = blockIdx.x;
  if (bid >= NP1) {
    // A writer: float4s CORNER4 .. 8388607 (corner written later by a_fix)
    long tid = (long)(bid - NP1) * 256 + threadIdx.x + CORNER4;
    write_A4(bp, Aout, tid);
    return;
  }
  // ---- phase1: wave (b,c) composes R := M_last ... M_first, c in 0..62 ----
  int wid  = bid * 4 + (threadIdx.x >> 6);
  int lane = threadIdx.x & 63;
  int g = lane >> 4, j = lane & 15;
  int b = wid & 31;
  int c = wid >> 5;                       // 0..62
  long t0 = (long)c * LCH + 1;
  const float* emb = em  + ((long)b * TT + t0) * KK;
  const float* bpb = bp  + (long)b * TT + t0;
  const float* mb  = msk + (long)b * TT + t0;

  float r0 = (j == 4*g + 0) ? 1.0f : 0.0f;
  float r1 = (j == 4*g + 1) ? 1.0f : 0.0f;
  float r2 = (j == 4*g + 2) ? 1.0f : 0.0f;
  float r3 = (j == 4*g + 3) ? 1.0f : 0.0f;

  float emv[4], bpv[4], mv[4];
  #pragma unroll
  for (int k = 0; k < 4; ++k) {
    emv[k] = emb[(long)k * KK + j]; bpv[k] = bpb[k]; mv[k] = mb[k];
  }
  for (int s0 = 0; s0 < LCH; s0 += 4) {
    float emn[4], bpn[4], mn[4];
    #pragma unroll
    for (int k = 0; k < 4; ++k) {
      int sn = s0 + 4 + k; if (sn > LCH - 1) sn = LCH - 1;
      emn[k] = emb[(long)sn * KK + j]; bpn[k] = bpb[sn]; mn[k] = mb[sn];
    }
    #pragma unroll
    for (int k = 0; k < 4; ++k) {
      float eta = fminf(fmaxf(fmaf(0.33f, bpv[k], 0.02f), 0.001f), 0.95f);
      float dm  = fmaxf((1.0f - eta) - RHO, 0.01f);
      float s0n = (1.0f - eta) + eta;
      float smn = (RHO + dm) + eta;
      float i0  = __builtin_amdgcn_rcpf(s0n);
      float im  = __builtin_amdgcn_rcpf(smn);
      float i_jm1 = (j == 1) ? i0 : im;
      float i_j   = (j == 0) ? i0 : ((j == 15) ? 1.0f : im);
      float i_jp1 = (j == 14) ? 1.0f : im;
      float diag  = (j == 0) ? (1.0f - eta) : ((j == 15) ? (1.0f - RHO) : dm);
      bool on  = (mv[k] != 0.0f);
      float cL = on ? eta  * i_jm1 : 0.0f;
      float cD = on ? diag * i_j   : 1.0f;
      float cR = on ? RHO  * i_jp1 : 0.0f;
      float E  = on ? __expf(emv[k]) : 1.0f;

      float pl0 = dppf<0x111>(r0), pr0 = dppf<0x101>(r0);
      float pl1 = dppf<0x111>(r1), pr1 = dppf<0x101>(r1);
      float pl2 = dppf<0x111>(r2), pr2 = dppf<0x101>(r2);
      float pl3 = dppf<0x111>(r3), pr3 = dppf<0x101>(r3);
      r0 = E * fmaf(pl0, cL, fmaf(r0, cD, pr0 * cR));
      r1 = E * fmaf(pl1, cL, fmaf(r1, cD, pr1 * cR));
      r2 = E * fmaf(pl2, cL, fmaf(r2, cD, pr2 * cR));
      r3 = E * fmaf(pl3, cL, fmaf(r3, cD, pr3 * cR));
    }
    // range-control rescale (every 4 steps; growth <= e^22 between rescales)
    float grand = sum16((r0 + r1) + (r2 + r3));
    grand += __shfl_xor(grand, 16);
    grand += __shfl_xor(grand, 32);
    float sc = __builtin_amdgcn_rcpf(grand);
    r0 *= sc; r1 *= sc; r2 *= sc; r3 *= sc;
    #pragma unroll
    for (int k = 0; k < 4; ++k) { emv[k] = emn[k]; bpv[k] = bpn[k]; mv[k] = mn[k]; }
  }
  float4 v; v.x = r0; v.y = r1; v.z = r2; v.w = r3;
  ((float4*)(Gbuf + ((long)(b * NCH + c) << 8)))[j * 4 + g] = v;
}

// ---------------- K2: chunk-level serial scan (verified r3) ----------------
__global__ __launch_bounds__(256) void phase2_kernel(
    const float* __restrict__ em, const float* __restrict__ msk,
    const float* __restrict__ Gbuf, float* __restrict__ Pst)
{
  int b    = blockIdx.x * 4 + (threadIdx.x >> 6);  // 0..31
  int lane = threadIdx.x & 63;
  int g = lane >> 4, j = lane & 15;

  float em0  = em[(long)b * TT * KK + j];
  float em00 = rdfirst(em0);
  float m0   = msk[(long)b * TT];
  float la_init = (j == 0) ? 0.0f : -1000000.0f;
  float la0 = m0 * ((la_init + em0) - em00) + (1.0f - m0) * la_init;
  float P   = __expf(la0);

  const int src = 20 * g;   // lane 16g+j pulls p_{4g+q}
  float4 grow = *((const float4*)(Gbuf + ((long)(b * NCH) << 8)) + (j * 4 + g));
  for (int c = 0; c < NCH; ++c) {
    if (lane < 16) Pst[((long)(b * NCH + c) << 4) + j] = P;
    if (c == NCH - 1) break;
    float4 gnext = grow;
    if (c + 1 < NCH - 1)
      gnext = *((const float4*)(Gbuf + ((long)(b * NCH + c + 1) << 8)) + (j * 4 + g));
    float p0 = __shfl(P, src + 0), p1 = __shfl(P, src + 1);
    float p2 = __shfl(P, src + 2), p3 = __shfl(P, src + 3);
    float up = grow.x * p0;
    up = fmaf(grow.y, p1, up);
    up = fmaf(grow.z, p2, up);
    up = fmaf(grow.w, p3, up);
    up += __shfl_xor(up, 16);
    up += __shfl_xor(up, 32);
    float S = sum16(up);
    P = up * __builtin_amdgcn_rcpf(S);
    grow = gnext;
  }
}

// ---------------- K3: replay, 4 distinct chunks per wave (verified r3) -----
__global__ __launch_bounds__(256) void phase3_kernel(
    const float* __restrict__ em, const float* __restrict__ bp,
    const float* __restrict__ msk, const float* __restrict__ Pst,
    float* __restrict__ out)
{
  const long BTK = (long)BB * TT * KK;
  float* beliefs = out;
  float* logb    = out + BTK;
  float* lzs     = out + 2 * BTK;

  int wid  = blockIdx.x * 4 + (threadIdx.x >> 6);   // 0..511
  int lane = threadIdx.x & 63;
  int j   = lane & 15;
  int row = lane >> 4;
  int b   = wid >> 4;                               // 0..31
  int c   = ((wid & 15) << 2) + row;                // 0..63 (per-row chunk)

  const float* emb = em  + (long)b * TT * KK;
  const float* bpb = bp  + (long)b * TT;
  const float* mb  = msk + (long)b * TT;
  float* belb = beliefs + (long)b * TT * KK;
  float* lbb  = logb    + (long)b * TT * KK;
  float* lzb  = lzs     + (long)b * TT;

  float P = Pst[((long)(b * NCH + c) << 4) + j];

  if (c == 0) {                                     // lanes 0..15 of wid%16==0
    float em0  = emb[j];
    float em00 = rdfirst(em0);
    float m0   = mb[0];
    float la_init = (j == 0) ? 0.0f : -1000000.0f;
    float la0 = m0 * ((la_init + em0) - em00) + (1.0f - m0) * la_init;
    belb[j] = P;
    lbb[j]  = la0;
    if (j == 0) lzb[0] = m0 * em00;
  }

  const int t0 = (c << 6) + 1;
  float emv[4], bpv[4], mv[4];
  #pragma unroll
  for (int k = 0; k < 4; ++k) {
    int ts = t0 + k; if (ts > TT - 1) ts = TT - 1;
    emv[k] = emb[(long)ts * KK + j]; bpv[k] = bpb[ts]; mv[k] = mb[ts];
  }
  for (int i0 = 0; i0 < LCH; i0 += 4) {
    float emn[4], bpn[4], mn[4];
    #pragma unroll
    for (int k = 0; k < 4; ++k) {
      int ts = t0 + i0 + 4 + k; if (ts > TT - 1) ts = TT - 1;
      emn[k] = emb[(long)ts * KK + j]; bpn[k] = bpb[ts]; mn[k] = mb[ts];
    }
    #pragma unroll
    for (int k = 0; k < 4; ++k) {
      int t = t0 + i0 + k;
      float eta = fminf(fmaxf(fmaf(0.33f, bpv[k], 0.02f), 0.001f), 0.95f);
      float dm  = fmaxf((1.0f - eta) - RHO, 0.01f);
      float s0n = (1.0f - eta) + eta;
      float smn = (RHO + dm) + eta;
      float i0r = __builtin_amdgcn_rcpf(s0n);
      float im  = __builtin_amdgcn_rcpf(smn);
      float i_jm1 = (j == 1) ? i0r : im;
      float i_j   = (j == 0) ? i0r : ((j == 15) ? 1.0f : im);
      float i_jp1 = (j == 14) ? 1.0f : im;
      float diag  = (j == 0) ? (1.0f - eta) : ((j == 15) ? (1.0f - RHO) : dm);
      float cL = fmaf(eta,  i_jm1, -LEAK);
      float cD = fmaf(diag, i_j,   -LEAK);
      float cR = fmaf(RHO,  i_jp1, -LEAK);
      float E  = __expf(emv[k]);

      float pl = dppf<0x111>(P), pr = dppf<0x101>(P);
      float pred = fmaf(pl, cL, fmaf(P, cD, fmaf(pr, cR, LEAK)));
      float u = pred * E;
      float S = sum16(u);
      float Pn = u * __builtin_amdgcn_rcpf(S);
      bool on = (mv[k] != 0.0f);
      if (t < TT) {
        P = on ? Pn : P;
        belb[(long)t * KK + j] = P;
        lbb[(long)t * KK + j]  = __logf(P);
        if (j == 0) lzb[t] = on ? __logf(S) : 0.0f;
      }
    }
    #pragma unroll
    for (int k = 0; k < 4; ++k) { emv[k] = emn[k]; bpv[k] = bpn[k]; mv[k] = mn[k]; }
  }
}

// ---------------- K4: rewrite the Pst corner of A (always runs) ------------
__global__ __launch_bounds__(256) void a_fix_kernel(
    const float* __restrict__ bp, float* __restrict__ Aout)
{
  long tid = (long)blockIdx.x * 256 + threadIdx.x;   // 0..8191 float4s
  write_A4(bp, Aout, tid);
}

extern "C" void kernel_launch(void* const* d_in, const int* in_sizes, int n_in,
                              void* d_out, int out_size, void* d_ws, size_t ws_size,
                              hipStream_t stream) {
  const float* em = (const float*)d_in[0];
  const float* bp = (const float*)d_in[1];
  const float* mk = (const float*)d_in[2];
  float* out = (float*)d_out;

  const long BTK = (long)BB * TT * KK;
  float* Gbuf = out;                               // stash G in beliefs region
  float* Aout = out + 2 * BTK + (long)BB * TT;
  float* Pst  = Aout;                              // 128KB stash in A corner

  hipLaunchKernelGGL(k1_fused,      dim3(NP1 + NA), dim3(256), 0, stream, em, bp, mk, Gbuf, Aout);
  hipLaunchKernelGGL(phase2_kernel, dim3(8),        dim3(256), 0, stream, em, mk, Gbuf, Pst);
  hipLaunchKernelGGL(phase3_kernel, dim3(128),      dim3(256), 0, stream, em, bp, mk, Pst, out);
  hipLaunchKernelGGL(a_fix_kernel,  dim3(32),       dim3(256), 0, stream, bp, Aout);
}

// Round 6
// 202.905 us; speedup vs baseline: 1.0282x; 1.0282x over previous
//
#include <hip/hip_runtime.h>

// NeuralHMM forward, B=32, T=4096, K=16, fp32.
// Outputs flat: beliefs[B,T,K], log_beliefs[B,T,K], log_normalizers[B,T], A[B,T,K,K]
//
// Chunked parallel scan, 3 kernels, no d_ws, no conditional launches:
//  D1 (fused): blocks 0..503 compose per-chunk 16x16 transfer operators G
//      (leak-free, rescale every 4 steps) into the LAST 2MB of the A region;
//      blocks 504+ write A (one float4/thread) skipping that tail.
//  D2: each wave recomputes the chunk-boundary alphas by scanning G itself
//      (full-wave matvec chain, capturing the 4 iterates its rows need), then
//      replays 4 distinct chunks (row-local DPP) writing beliefs/logb/lznorm.
//  D3: g_fix rewrites the 2MB A tail (after D2 consumed the G stash).

#define BB 32
#define TT 4096
#define KK 16
#define LCH 64
#define NCH 64
#define NP1 504           // phase1 blocks in fused kernel
#define NA  32256         // A-writer blocks in D1 (8257536 float4s)
#define GOFF4 8257536L    // float4 offset of G stash inside A region

constexpr float RHO  = 0.001f;
constexpr float LEAK = 1e-10f;

template<int CTRL>
__device__ __forceinline__ float dppf(float x) {
  return __uint_as_float((unsigned)__builtin_amdgcn_update_dpp(
      0, (int)__float_as_uint(x), CTRL, 0xF, 0xF, true));
}
// sum across each 16-lane row (row-local; all lanes get the row total)
__device__ __forceinline__ float sum16(float x) {
  x += dppf<0xB1>(x);   // xor 1
  x += dppf<0x4E>(x);   // xor 2
  x += dppf<0x141>(x);  // xor 7
  x += dppf<0x140>(x);  // xor 15
  return x;
}
__device__ __forceinline__ float rdfirst(float x) {
  return __uint_as_float((unsigned)__builtin_amdgcn_readfirstlane((int)__float_as_uint(x)));
}

__device__ __forceinline__ void write_A4(const float* __restrict__ bp,
                                         float* __restrict__ Aout, long tid) {
  long flat = tid * 4;
  int  bt   = (int)(flat >> 8);
  int  rem  = (int)(flat & 255);
  int  r    = rem >> 4;
  int  c0   = rem & 15;
  float p   = bp[bt];
  float eta = fminf(fmaxf(0.02f + 0.33f * p, 0.001f), 0.95f);
  float diag, s;
  if (r == 0)       { diag = 1.0f - eta; s = (1.0f - eta) + eta; }
  else if (r == 15) { diag = 1.0f - RHO; s = RHO + (1.0f - RHO); }
  else { diag = fmaxf((1.0f - eta) - RHO, 0.01f); s = (RHO + diag) + eta; }
  s = fmaxf(s, 1e-8f);
  float inv = 1.0f / s;
  float4 v;
  float* vp = &v.x;
  #pragma unroll
  for (int q = 0; q < 4; ++q) {
    int cc = c0 + q;
    float a = (cc == r) ? diag : (cc == r + 1) ? eta : (cc == r - 1) ? RHO : 0.0f;
    vp[q] = a * inv;
  }
  ((float4*)Aout)[tid] = v;
}

// ---------------- D1: chunk composition (to A tail) + A writer ----------------
__global__ __launch_bounds__(256) void k1_fused(
    const float* __restrict__ em, const float* __restrict__ bp,
    const float* __restrict__ msk, float* __restrict__ Gst,
    float* __restrict__ Aout)
{
  const int bid = blockIdx.x;
  if (bid >= NP1) {
    // A writer: float4s 0 .. GOFF4-1 (tail holds G, rewritten later by g_fix)
    long tid = (long)(bid - NP1) * 256 + threadIdx.x;
    write_A4(bp, Aout, tid);
    return;
  }
  // ---- phase1: wave (b,c) composes R := M_last ... M_first, c in 0..62 ----
  int wid  = bid * 4 + (threadIdx.x >> 6);
  int lane = threadIdx.x & 63;
  int g = lane >> 4, j = lane & 15;
  int b = wid & 31;
  int c = wid >> 5;                       // 0..62
  long t0 = (long)c * LCH + 1;
  const float* emb = em  + ((long)b * TT + t0) * KK;
  const float* bpb = bp  + (long)b * TT + t0;
  const float* mb  = msk + (long)b * TT + t0;

  float r0 = (j == 4*g + 0) ? 1.0f : 0.0f;
  float r1 = (j == 4*g + 1) ? 1.0f : 0.0f;
  float r2 = (j == 4*g + 2) ? 1.0f : 0.0f;
  float r3 = (j == 4*g + 3) ? 1.0f : 0.0f;

  float emv[4], bpv[4], mv[4];
  #pragma unroll
  for (int k = 0; k < 4; ++k) {
    emv[k] = emb[(long)k * KK + j]; bpv[k] = bpb[k]; mv[k] = mb[k];
  }
  for (int s0 = 0; s0 < LCH; s0 += 4) {
    float emn[4], bpn[4], mn[4];
    #pragma unroll
    for (int k = 0; k < 4; ++k) {
      int sn = s0 + 4 + k; if (sn > LCH - 1) sn = LCH - 1;
      emn[k] = emb[(long)sn * KK + j]; bpn[k] = bpb[sn]; mn[k] = mb[sn];
    }
    #pragma unroll
    for (int k = 0; k < 4; ++k) {
      float eta = fminf(fmaxf(fmaf(0.33f, bpv[k], 0.02f), 0.001f), 0.95f);
      float dm  = fmaxf((1.0f - eta) - RHO, 0.01f);
      float s0n = (1.0f - eta) + eta;
      float smn = (RHO + dm) + eta;
      float i0  = __builtin_amdgcn_rcpf(s0n);
      float im  = __builtin_amdgcn_rcpf(smn);
      float i_jm1 = (j == 1) ? i0 : im;
      float i_j   = (j == 0) ? i0 : ((j == 15) ? 1.0f : im);
      float i_jp1 = (j == 14) ? 1.0f : im;
      float diag  = (j == 0) ? (1.0f - eta) : ((j == 15) ? (1.0f - RHO) : dm);
      bool on  = (mv[k] != 0.0f);
      float cL = on ? eta  * i_jm1 : 0.0f;
      float cD = on ? diag * i_j   : 1.0f;
      float cR = on ? RHO  * i_jp1 : 0.0f;
      float E  = on ? __expf(emv[k]) : 1.0f;

      float pl0 = dppf<0x111>(r0), pr0 = dppf<0x101>(r0);
      float pl1 = dppf<0x111>(r1), pr1 = dppf<0x101>(r1);
      float pl2 = dppf<0x111>(r2), pr2 = dppf<0x101>(r2);
      float pl3 = dppf<0x111>(r3), pr3 = dppf<0x101>(r3);
      r0 = E * fmaf(pl0, cL, fmaf(r0, cD, pr0 * cR));
      r1 = E * fmaf(pl1, cL, fmaf(r1, cD, pr1 * cR));
      r2 = E * fmaf(pl2, cL, fmaf(r2, cD, pr2 * cR));
      r3 = E * fmaf(pl3, cL, fmaf(r3, cD, pr3 * cR));
    }
    // range-control rescale (every 4 steps; growth <= e^22 between rescales)
    float grand = sum16((r0 + r1) + (r2 + r3));
    grand += __shfl_xor(grand, 16);
    grand += __shfl_xor(grand, 32);
    float sc = __builtin_amdgcn_rcpf(grand);
    r0 *= sc; r1 *= sc; r2 *= sc; r3 *= sc;
    #pragma unroll
    for (int k = 0; k < 4; ++k) { emv[k] = emn[k]; bpv[k] = bpn[k]; mv[k] = mn[k]; }
  }
  float4 v; v.x = r0; v.y = r1; v.z = r2; v.w = r3;
  ((float4*)(Gst + ((long)(b * NCH + c) << 8)))[j * 4 + g] = v;
}

// ---------------- D2: chain-recompute + replay (phase2 merged in) ----------
__global__ __launch_bounds__(256) void phase3_kernel(
    const float* __restrict__ em, const float* __restrict__ bp,
    const float* __restrict__ msk, const float* __restrict__ Gst,
    float* __restrict__ out)
{
  const long BTK = (long)BB * TT * KK;
  float* beliefs = out;
  float* logb    = out + BTK;
  float* lzs     = out + 2 * BTK;

  int wid  = blockIdx.x * 4 + (threadIdx.x >> 6);   // 0..511
  int lane = threadIdx.x & 63;
  int j   = lane & 15;
  int row = lane >> 4;                              // = g
  int b   = wid >> 4;                               // 0..31
  int cb  = (wid & 15) << 2;                        // chunk base 0,4,..,60

  const float* emb = em  + (long)b * TT * KK;
  const float* bpb = bp  + (long)b * TT;
  const float* mb  = msk + (long)b * TT;
  float* belb = beliefs + (long)b * TT * KK;
  float* lbb  = logb    + (long)b * TT * KK;
  float* lzb  = lzs     + (long)b * TT;

  // ---- t=0 closed form: P0 replicated on all rows (j-only math) ----
  float em0  = emb[j];
  float em00 = rdfirst(em0);
  float m0   = mb[0];
  float la_init = (j == 0) ? 0.0f : -1000000.0f;
  float la0 = m0 * ((la_init + em0) - em00) + (1.0f - m0) * la_init;
  float P   = __expf(la0);

  // ---- chunk-operator chain (phase2 math), capture the 4 iterates we need ----
  float Pcap = P;
  const int src = 20 * row;     // lane 16g+j pulls p_{4g+q} (P is row-replicated)
  const int cstop = cb + 3;     // last capture index (<= 63)
  float4 grow = ((const float4*)(Gst))[((long)(b * NCH) << 6) + j * 4 + row];
  for (int c = 0; ; ++c) {
    if (c == cb + row) Pcap = P;
    if (c == cstop) break;
    float4 gnx = grow;
    if (c + 1 < cstop)          // prefetch G[b][c+1] (max index 62)
      gnx = ((const float4*)(Gst))[((long)(b * NCH + c + 1) << 6) + j * 4 + row];
    float p0 = __shfl(P, src + 0), p1 = __shfl(P, src + 1);
    float p2 = __shfl(P, src + 2), p3 = __shfl(P, src + 3);
    float up = grow.x * p0;
    up = fmaf(grow.y, p1, up);
    up = fmaf(grow.z, p2, up);
    up = fmaf(grow.w, p3, up);
    up += __shfl_xor(up, 16);
    up += __shfl_xor(up, 32);
    float S = sum16(up);
    P = up * __builtin_amdgcn_rcpf(S);
    grow = gnx;
  }
  P = Pcap;
  const int c = cb + row;                           // this row's chunk (0..63)

  if (cb == 0 && lane < 16) {                       // chunk 0, row 0 writes t=0
    belb[j] = P;
    lbb[j]  = la0;
    if (j == 0) lzb[0] = m0 * em00;
  }

  // ---- 64-step replay (verified r3 math) ----
  const int t0 = (c << 6) + 1;
  float emv[4], bpv[4], mv[4];
  #pragma unroll
  for (int k = 0; k < 4; ++k) {
    int ts = t0 + k; if (ts > TT - 1) ts = TT - 1;
    emv[k] = emb[(long)ts * KK + j]; bpv[k] = bpb[ts]; mv[k] = mb[ts];
  }
  for (int i0 = 0; i0 < LCH; i0 += 4) {
    float emn[4], bpn[4], mn[4];
    #pragma unroll
    for (int k = 0; k < 4; ++k) {
      int ts = t0 + i0 + 4 + k; if (ts > TT - 1) ts = TT - 1;
      emn[k] = emb[(long)ts * KK + j]; bpn[k] = bpb[ts]; mn[k] = mb[ts];
    }
    #pragma unroll
    for (int k = 0; k < 4; ++k) {
      int t = t0 + i0 + k;
      float eta = fminf(fmaxf(fmaf(0.33f, bpv[k], 0.02f), 0.001f), 0.95f);
      float dm  = fmaxf((1.0f - eta) - RHO, 0.01f);
      float s0n = (1.0f - eta) + eta;
      float smn = (RHO + dm) + eta;
      float i0r = __builtin_amdgcn_rcpf(s0n);
      float im  = __builtin_amdgcn_rcpf(smn);
      float i_jm1 = (j == 1) ? i0r : im;
      float i_j   = (j == 0) ? i0r : ((j == 15) ? 1.0f : im);
      float i_jp1 = (j == 14) ? 1.0f : im;
      float diag  = (j == 0) ? (1.0f - eta) : ((j == 15) ? (1.0f - RHO) : dm);
      float cL = fmaf(eta,  i_jm1, -LEAK);
      float cD = fmaf(diag, i_j,   -LEAK);
      float cR = fmaf(RHO,  i_jp1, -LEAK);
      float E  = __expf(emv[k]);

      float pl = dppf<0x111>(P), pr = dppf<0x101>(P);
      float pred = fmaf(pl, cL, fmaf(P, cD, fmaf(pr, cR, LEAK)));
      float u = pred * E;
      float S = sum16(u);
      float Pn = u * __builtin_amdgcn_rcpf(S);
      bool on = (mv[k] != 0.0f);
      if (t < TT) {
        P = on ? Pn : P;
        belb[(long)t * KK + j] = P;
        lbb[(long)t * KK + j]  = __logf(P);
        if (j == 0) lzb[t] = on ? __logf(S) : 0.0f;
      }
    }
    #pragma unroll
    for (int k = 0; k < 4; ++k) { emv[k] = emn[k]; bpv[k] = bpn[k]; mv[k] = mn[k]; }
  }
}

// ---------------- D3: rewrite the G-stash tail of A (always runs) ----------
__global__ __launch_bounds__(256) void g_fix_kernel(
    const float* __restrict__ bp, float* __restrict__ Aout)
{
  long tid = GOFF4 + (long)blockIdx.x * 256 + threadIdx.x;  // 131072 float4s
  write_A4(bp, Aout, tid);
}

extern "C" void kernel_launch(void* const* d_in, const int* in_sizes, int n_in,
                              void* d_out, int out_size, void* d_ws, size_t ws_size,
                              hipStream_t stream) {
  const float* em = (const float*)d_in[0];
  const float* bp = (const float*)d_in[1];
  const float* mk = (const float*)d_in[2];
  float* out = (float*)d_out;

  const long BTK = (long)BB * TT * KK;
  float* Aout = out + 2 * BTK + (long)BB * TT;
  float* Gst  = Aout + GOFF4 * 4;                  // last 2MB of A region

  hipLaunchKernelGGL(k1_fused,      dim3(NP1 + NA), dim3(256), 0, stream, em, bp, mk, Gst, Aout);
  hipLaunchKernelGGL(phase3_kernel, dim3(128),      dim3(256), 0, stream, em, bp, mk, Gst, out);
  hipLaunchKernelGGL(g_fix_kernel,  dim3(512),      dim3(256), 0, stream, bp, Aout);
}

// Round 8
// 202.781 us; speedup vs baseline: 1.0288x; 1.0006x over previous
//
#include <hip/hip_runtime.h>

// NeuralHMM forward, B=32, T=4096, K=16, fp32.
// Outputs flat: beliefs[B,T,K], log_beliefs[B,T,K], log_normalizers[B,T], A[B,T,K,K]
//
// Chunked parallel scan, 3 kernels, no d_ws, no conditional launches:
//  D1 (fused): blocks 0..503 compose per-chunk 16x16 transfer operators G
//      (leak-free, rescale every 4 steps) into the LAST 2MB of the A region;
//      blocks 504+ write A (one float4/thread) skipping that tail.
//  D2: each wave recomputes the chunk-boundary alphas by scanning G itself
//      (full-wave matvec chain, capturing the 4 iterates its rows need), then
//      replays 4 distinct chunks (row-local DPP) writing beliefs/logb/lznorm.
//  D3: g_fix rewrites the 2MB A tail (after D2 consumed the G stash).
//
// NOTE (r7): hipLaunchCooperativeKernel silently fails under this harness's
// graph-capture replay — outputs never written. Plain stream launches only.

#define BB 32
#define TT 4096
#define KK 16
#define LCH 64
#define NCH 64
#define NP1 504           // phase1 blocks in fused kernel
#define NA  32256         // A-writer blocks in D1 (8257536 float4s)
#define GOFF4 8257536L    // float4 offset of G stash inside A region

constexpr float RHO  = 0.001f;
constexpr float LEAK = 1e-10f;

template<int CTRL>
__device__ __forceinline__ float dppf(float x) {
  return __uint_as_float((unsigned)__builtin_amdgcn_update_dpp(
      0, (int)__float_as_uint(x), CTRL, 0xF, 0xF, true));
}
// sum across each 16-lane row (row-local; all lanes get the row total)
__device__ __forceinline__ float sum16(float x) {
  x += dppf<0xB1>(x);   // xor 1
  x += dppf<0x4E>(x);   // xor 2
  x += dppf<0x141>(x);  // xor 7
  x += dppf<0x140>(x);  // xor 15
  return x;
}
__device__ __forceinline__ float rdfirst(float x) {
  return __uint_as_float((unsigned)__builtin_amdgcn_readfirstlane((int)__float_as_uint(x)));
}

__device__ __forceinline__ void write_A4(const float* __restrict__ bp,
                                         float* __restrict__ Aout, long tid) {
  long flat = tid * 4;
  int  bt   = (int)(flat >> 8);
  int  rem  = (int)(flat & 255);
  int  r    = rem >> 4;
  int  c0   = rem & 15;
  float p   = bp[bt];
  float eta = fminf(fmaxf(0.02f + 0.33f * p, 0.001f), 0.95f);
  float diag, s;
  if (r == 0)       { diag = 1.0f - eta; s = (1.0f - eta) + eta; }
  else if (r == 15) { diag = 1.0f - RHO; s = RHO + (1.0f - RHO); }
  else { diag = fmaxf((1.0f - eta) - RHO, 0.01f); s = (RHO + diag) + eta; }
  s = fmaxf(s, 1e-8f);
  float inv = 1.0f / s;
  float4 v;
  float* vp = &v.x;
  #pragma unroll
  for (int q = 0; q < 4; ++q) {
    int cc = c0 + q;
    float a = (cc == r) ? diag : (cc == r + 1) ? eta : (cc == r - 1) ? RHO : 0.0f;
    vp[q] = a * inv;
  }
  ((float4*)Aout)[tid] = v;
}

// ---------------- D1: chunk composition (to A tail) + A writer ----------------
__global__ __launch_bounds__(256) void k1_fused(
    const float* __restrict__ em, const float* __restrict__ bp,
    const float* __restrict__ msk, float* __restrict__ Gst,
    float* __restrict__ Aout)
{
  const int bid = blockIdx.x;
  if (bid >= NP1) {
    // A writer: float4s 0 .. GOFF4-1 (tail holds G, rewritten later by g_fix)
    long tid = (long)(bid - NP1) * 256 + threadIdx.x;
    write_A4(bp, Aout, tid);
    return;
  }
  // ---- phase1: wave (b,c) composes R := M_last ... M_first, c in 0..62 ----
  int wid  = bid * 4 + (threadIdx.x >> 6);
  int lane = threadIdx.x & 63;
  int g = lane >> 4, j = lane & 15;
  int b = wid & 31;
  int c = wid >> 5;                       // 0..62
  long t0 = (long)c * LCH + 1;
  const float* emb = em  + ((long)b * TT + t0) * KK;
  const float* bpb = bp  + (long)b * TT + t0;
  const float* mb  = msk + (long)b * TT + t0;

  float r0 = (j == 4*g + 0) ? 1.0f : 0.0f;
  float r1 = (j == 4*g + 1) ? 1.0f : 0.0f;
  float r2 = (j == 4*g + 2) ? 1.0f : 0.0f;
  float r3 = (j == 4*g + 3) ? 1.0f : 0.0f;

  float emv[4], bpv[4], mv[4];
  #pragma unroll
  for (int k = 0; k < 4; ++k) {
    emv[k] = emb[(long)k * KK + j]; bpv[k] = bpb[k]; mv[k] = mb[k];
  }
  for (int s0 = 0; s0 < LCH; s0 += 4) {
    float emn[4], bpn[4], mn[4];
    #pragma unroll
    for (int k = 0; k < 4; ++k) {
      int sn = s0 + 4 + k; if (sn > LCH - 1) sn = LCH - 1;
      emn[k] = emb[(long)sn * KK + j]; bpn[k] = bpb[sn]; mn[k] = mb[sn];
    }
    #pragma unroll
    for (int k = 0; k < 4; ++k) {
      float eta = fminf(fmaxf(fmaf(0.33f, bpv[k], 0.02f), 0.001f), 0.95f);
      float dm  = fmaxf((1.0f - eta) - RHO, 0.01f);
      float s0n = (1.0f - eta) + eta;
      float smn = (RHO + dm) + eta;
      float i0  = __builtin_amdgcn_rcpf(s0n);
      float im  = __builtin_amdgcn_rcpf(smn);
      float i_jm1 = (j == 1) ? i0 : im;
      float i_j   = (j == 0) ? i0 : ((j == 15) ? 1.0f : im);
      float i_jp1 = (j == 14) ? 1.0f : im;
      float diag  = (j == 0) ? (1.0f - eta) : ((j == 15) ? (1.0f - RHO) : dm);
      bool on  = (mv[k] != 0.0f);
      float cL = on ? eta  * i_jm1 : 0.0f;
      float cD = on ? diag * i_j   : 1.0f;
      float cR = on ? RHO  * i_jp1 : 0.0f;
      float E  = on ? __expf(emv[k]) : 1.0f;

      float pl0 = dppf<0x111>(r0), pr0 = dppf<0x101>(r0);
      float pl1 = dppf<0x111>(r1), pr1 = dppf<0x101>(r1);
      float pl2 = dppf<0x111>(r2), pr2 = dppf<0x101>(r2);
      float pl3 = dppf<0x111>(r3), pr3 = dppf<0x101>(r3);
      r0 = E * fmaf(pl0, cL, fmaf(r0, cD, pr0 * cR));
      r1 = E * fmaf(pl1, cL, fmaf(r1, cD, pr1 * cR));
      r2 = E * fmaf(pl2, cL, fmaf(r2, cD, pr2 * cR));
      r3 = E * fmaf(pl3, cL, fmaf(r3, cD, pr3 * cR));
    }
    // range-control rescale (every 4 steps; growth <= e^22 between rescales)
    float grand = sum16((r0 + r1) + (r2 + r3));
    grand += __shfl_xor(grand, 16);
    grand += __shfl_xor(grand, 32);
    float sc = __builtin_amdgcn_rcpf(grand);
    r0 *= sc; r1 *= sc; r2 *= sc; r3 *= sc;
    #pragma unroll
    for (int k = 0; k < 4; ++k) { emv[k] = emn[k]; bpv[k] = bpn[k]; mv[k] = mn[k]; }
  }
  float4 v; v.x = r0; v.y = r1; v.z = r2; v.w = r3;
  ((float4*)(Gst + ((long)(b * NCH + c) << 8)))[j * 4 + g] = v;
}

// ---------------- D2: chain-recompute + replay (phase2 merged in) ----------
__global__ __launch_bounds__(256) void phase3_kernel(
    const float* __restrict__ em, const float* __restrict__ bp,
    const float* __restrict__ msk, const float* __restrict__ Gst,
    float* __restrict__ out)
{
  const long BTK = (long)BB * TT * KK;
  float* beliefs = out;
  float* logb    = out + BTK;
  float* lzs     = out + 2 * BTK;

  int wid  = blockIdx.x * 4 + (threadIdx.x >> 6);   // 0..511
  int lane = threadIdx.x & 63;
  int j   = lane & 15;
  int row = lane >> 4;                              // = g
  int b   = wid >> 4;                               // 0..31
  int cb  = (wid & 15) << 2;                        // chunk base 0,4,..,60

  const float* emb = em  + (long)b * TT * KK;
  const float* bpb = bp  + (long)b * TT;
  const float* mb  = msk + (long)b * TT;
  float* belb = beliefs + (long)b * TT * KK;
  float* lbb  = logb    + (long)b * TT * KK;
  float* lzb  = lzs     + (long)b * TT;

  // ---- t=0 closed form: P0 replicated on all rows (j-only math) ----
  float em0  = emb[j];
  float em00 = rdfirst(em0);
  float m0   = mb[0];
  float la_init = (j == 0) ? 0.0f : -1000000.0f;
  float la0 = m0 * ((la_init + em0) - em00) + (1.0f - m0) * la_init;
  float P   = __expf(la0);

  // ---- chunk-operator chain (phase2 math), capture the 4 iterates we need ----
  float Pcap = P;
  const int src = 20 * row;     // lane 16g+j pulls p_{4g+q} (P is row-replicated)
  const int cstop = cb + 3;     // last capture index (<= 63)
  float4 grow = ((const float4*)(Gst))[((long)(b * NCH) << 6) + j * 4 + row];
  for (int c = 0; ; ++c) {
    if (c == cb + row) Pcap = P;
    if (c == cstop) break;
    float4 gnx = grow;
    if (c + 1 < cstop)          // prefetch G[b][c+1] (max index 62)
      gnx = ((const float4*)(Gst))[((long)(b * NCH + c + 1) << 6) + j * 4 + row];
    float p0 = __shfl(P, src + 0), p1 = __shfl(P, src + 1);
    float p2 = __shfl(P, src + 2), p3 = __shfl(P, src + 3);
    float up = grow.x * p0;
    up = fmaf(grow.y, p1, up);
    up = fmaf(grow.z, p2, up);
    up = fmaf(grow.w, p3, up);
    up += __shfl_xor(up, 16);
    up += __shfl_xor(up, 32);
    float S = sum16(up);
    P = up * __builtin_amdgcn_rcpf(S);
    grow = gnx;
  }
  P = Pcap;
  const int c = cb + row;                           // this row's chunk (0..63)

  if (cb == 0 && lane < 16) {                       // chunk 0, row 0 writes t=0
    belb[j] = P;
    lbb[j]  = la0;
    if (j == 0) lzb[0] = m0 * em00;
  }

  // ---- 64-step replay (verified r3 math) ----
  const int t0 = (c << 6) + 1;
  float emv[4], bpv[4], mv[4];
  #pragma unroll
  for (int k = 0; k < 4; ++k) {
    int ts = t0 + k; if (ts > TT - 1) ts = TT - 1;
    emv[k] = emb[(long)ts * KK + j]; bpv[k] = bpb[ts]; mv[k] = mb[ts];
  }
  for (int i0 = 0; i0 < LCH; i0 += 4) {
    float emn[4], bpn[4], mn[4];
    #pragma unroll
    for (int k = 0; k < 4; ++k) {
      int ts = t0 + i0 + 4 + k; if (ts > TT - 1) ts = TT - 1;
      emn[k] = emb[(long)ts * KK + j]; bpn[k] = bpb[ts]; mn[k] = mb[ts];
    }
    #pragma unroll
    for (int k = 0; k < 4; ++k) {
      int t = t0 + i0 + k;
      float eta = fminf(fmaxf(fmaf(0.33f, bpv[k], 0.02f), 0.001f), 0.95f);
      float dm  = fmaxf((1.0f - eta) - RHO, 0.01f);
      float s0n = (1.0f - eta) + eta;
      float smn = (RHO + dm) + eta;
      float i0r = __builtin_amdgcn_rcpf(s0n);
      float im  = __builtin_amdgcn_rcpf(smn);
      float i_jm1 = (j == 1) ? i0r : im;
      float i_j   = (j == 0) ? i0r : ((j == 15) ? 1.0f : im);
      float i_jp1 = (j == 14) ? 1.0f : im;
      float diag  = (j == 0) ? (1.0f - eta) : ((j == 15) ? (1.0f - RHO) : dm);
      float cL = fmaf(eta,  i_jm1, -LEAK);
      float cD = fmaf(diag, i_j,   -LEAK);
      float cR = fmaf(RHO,  i_jp1, -LEAK);
      float E  = __expf(emv[k]);

      float pl = dppf<0x111>(P), pr = dppf<0x101>(P);
      float pred = fmaf(pl, cL, fmaf(P, cD, fmaf(pr, cR, LEAK)));
      float u = pred * E;
      float S = sum16(u);
      float Pn = u * __builtin_amdgcn_rcpf(S);
      bool on = (mv[k] != 0.0f);
      if (t < TT) {
        P = on ? Pn : P;
        belb[(long)t * KK + j] = P;
        lbb[(long)t * KK + j]  = __logf(P);
        if (j == 0) lzb[t] = on ? __logf(S) : 0.0f;
      }
    }
    #pragma unroll
    for (int k = 0; k < 4; ++k) { emv[k] = emn[k]; bpv[k] = bpn[k]; mv[k] = mn[k]; }
  }
}

// ---------------- D3: rewrite the G-stash tail of A (always runs) ----------
__global__ __launch_bounds__(256) void g_fix_kernel(
    const float* __restrict__ bp, float* __restrict__ Aout)
{
  long tid = GOFF4 + (long)blockIdx.x * 256 + threadIdx.x;  // 131072 float4s
  write_A4(bp, Aout, tid);
}

extern "C" void kernel_launch(void* const* d_in, const int* in_sizes, int n_in,
                              void* d_out, int out_size, void* d_ws, size_t ws_size,
                              hipStream_t stream) {
  const float* em = (const float*)d_in[0];
  const float* bp = (const float*)d_in[1];
  const float* mk = (const float*)d_in[2];
  float* out = (float*)d_out;

  const long BTK = (long)BB * TT * KK;
  float* Aout = out + 2 * BTK + (long)BB * TT;
  float* Gst  = Aout + GOFF4 * 4;                  // last 2MB of A region

  hipLaunchKernelGGL(k1_fused,      dim3(NP1 + NA), dim3(256), 0, stream, em, bp, mk, Gst, Aout);
  hipLaunchKernelGGL(phase3_kernel, dim3(128),      dim3(256), 0, stream, em, bp, mk, Gst, out);
  hipLaunchKernelGGL(g_fix_kernel,  dim3(512),      dim3(256), 0, stream, bp, Aout);
}